// Round 10
// baseline (137.184 us; speedup 1.0000x reference)
//
#include <hip/hip_runtime.h>

#define NB 4
#define SEQ 2048
#define EMB 32
#define HEADS 8
#define HD 4

typedef float v2f __attribute__((ext_vector_type(2)));
typedef unsigned int uint;

__device__ __forceinline__ v2f splat2(float x) { v2f r; r.x = x; r.y = x; return r; }
__device__ __forceinline__ v2f pkfma(v2f a, v2f b, v2f c) {
  return __builtin_elementwise_fma(a, b, c);
}

// Fused: mask bit-pack (blocks [0, 16384)) + K/V projections (blocks after).
__global__ __launch_bounds__(256) void pack_proj_kernel(
    const int* __restrict__ mask, uint* __restrict__ pmw,
    const float* __restrict__ key, const float* __restrict__ value,
    const float* __restrict__ Wk, const float* __restrict__ bk,
    const float* __restrict__ Wv, const float* __restrict__ bv,
    float* __restrict__ Kp, float* __restrict__ Vp) {
  const int packBlocks = NB * SEQ * SEQ / 4 / 256;   // 16384
  if (blockIdx.x < packBlocks) {
    // mask (N,1,Q,K) int32 -> 1 bit per key (bit b of word w = key 32w+b).
    int g = blockIdx.x * 256 + threadIdx.x;          // int4 index
    const int4 v = ((const int4*)mask)[g];
    uint nib = (uint)(v.x != 0) | ((uint)(v.y != 0) << 1) |
               ((uint)(v.z != 0) << 2) | ((uint)(v.w != 0) << 3);
    int lane = threadIdx.x & 63;
    uint w = nib << (4 * (lane & 7));
    w |= __shfl_xor(w, 1);
    w |= __shfl_xor(w, 2);
    w |= __shfl_xor(w, 4);
    if ((lane & 7) == 0) pmw[g >> 3] = w;
  } else {
    const int half = NB * SEQ / 8;                   // 1024
    int blk2 = blockIdx.x - packBlocks;
    bool isV = blk2 >= half;
    const float* X = isV ? value : key;
    const float* W = isV ? Wv : Wk;
    const float* b = isV ? bv : bk;
    float* P = isV ? Vp : Kp;
    int blk = isV ? (blk2 - half) : blk2;

    __shared__ float sW[EMB][EMB];
    __shared__ float sb[EMB];
    __shared__ float sX[8][EMB];
    int t = threadIdx.x;
    for (int i = t; i < EMB * EMB; i += 256) sW[i >> 5][i & 31] = W[i];
    if (t < EMB) sb[t] = b[t];
    size_t row0 = (size_t)blk * 8;
    int r = t >> 5, c = t & 31;
    sX[r][c] = X[(row0 + r) * EMB + c];
    __syncthreads();
    float acc = sb[c];
#pragma unroll
    for (int d = 0; d < EMB; ++d) acc = fmaf(sX[r][d], sW[d][c], acc);
    P[(row0 + r) * EMB + c] = acc;
  }
}

// 16-key tile: KK[j]/VV[j] hold key (4*ks + j)'s dims 4h..4h+3.
// rp half-waves issue identical addresses (hardware merges cache-line work).
__device__ __forceinline__ void load_tile16(
    const float*& kptr, const float*& vptr,
    float4 (&KK)[4], float4 (&VV)[4]) {
  KK[0] = *(const float4*)(kptr);
  KK[1] = *(const float4*)(kptr + EMB);
  KK[2] = *(const float4*)(kptr + 2 * EMB);
  KK[3] = *(const float4*)(kptr + 3 * EMB);
  VV[0] = *(const float4*)(vptr);
  VV[1] = *(const float4*)(vptr + EMB);
  VV[2] = *(const float4*)(vptr + 2 * EMB);
  VV[3] = *(const float4*)(vptr + 3 * EMB);
  kptr += 16 * EMB; vptr += 16 * EMB;
}

// No-max softmax, no mask (fast path): p = exp2(s).
__device__ __forceinline__ void compute_tile16(
    const float4 (&KK)[4], const float4 (&VV)[4],
    const v2f (&q2)[2][4], v2f (&l2)[2], v2f (&ac2)[2][4]) {
  v2f pf[2][4];
#pragma unroll
  for (int p = 0; p < 2; ++p) {
#pragma unroll
    for (int j = 0; j < 4; ++j) {
      const float4 kk = KK[j];
      v2f s = pkfma(q2[p][0], splat2(kk.x),
              pkfma(q2[p][1], splat2(kk.y),
              pkfma(q2[p][2], splat2(kk.z), q2[p][3] * splat2(kk.w))));
      pf[p][j].x = __builtin_amdgcn_exp2f(s.x);
      pf[p][j].y = __builtin_amdgcn_exp2f(s.y);
    }
  }
#pragma unroll
  for (int p = 0; p < 2; ++p) {
    l2[p] += (pf[p][0] + pf[p][1]) + (pf[p][2] + pf[p][3]);
#pragma unroll
    for (int j = 0; j < 4; ++j) {
      const float4 vv = VV[j];
      ac2[p][0] = pkfma(pf[p][j], splat2(vv.x), ac2[p][0]);
      ac2[p][1] = pkfma(pf[p][j], splat2(vv.y), ac2[p][1]);
      ac2[p][2] = pkfma(pf[p][j], splat2(vv.z), ac2[p][2]);
      ac2[p][3] = pkfma(pf[p][j], splat2(vv.w), ac2[p][3]);
    }
  }
}

// Masked variant (cold path; bench mask is all-ones so rarely taken).
__device__ __forceinline__ void compute_tile16_masked(
    const float4 (&KK)[4], const float4 (&VV)[4],
    const uint (&MW)[4], int tile, int ks,
    const v2f (&q2)[2][4], v2f (&l2)[2], v2f (&ac2)[2][4]) {
  v2f pf[2][4];
  int shb = 16 * (tile & 1) + 4 * ks;
#pragma unroll
  for (int p = 0; p < 2; ++p) {
#pragma unroll
    for (int j = 0; j < 4; ++j) {
      const float4 kk = KK[j];
      v2f s = pkfma(q2[p][0], splat2(kk.x),
              pkfma(q2[p][1], splat2(kk.y),
              pkfma(q2[p][2], splat2(kk.z), q2[p][3] * splat2(kk.w))));
      pf[p][j].x = ((MW[2 * p + 0] >> (shb + j)) & 1u) ? __builtin_amdgcn_exp2f(s.x) : 0.0f;
      pf[p][j].y = ((MW[2 * p + 1] >> (shb + j)) & 1u) ? __builtin_amdgcn_exp2f(s.y) : 0.0f;
    }
  }
#pragma unroll
  for (int p = 0; p < 2; ++p) {
    l2[p] += (pf[p][0] + pf[p][1]) + (pf[p][2] + pf[p][3]);
#pragma unroll
    for (int j = 0; j < 4; ++j) {
      const float4 vv = VV[j];
      ac2[p][0] = pkfma(pf[p][j], splat2(vv.x), ac2[p][0]);
      ac2[p][1] = pkfma(pf[p][j], splat2(vv.y), ac2[p][1]);
      ac2[p][2] = pkfma(pf[p][j], splat2(vv.z), ac2[p][2]);
      ac2[p][3] = pkfma(pf[p][j], splat2(vv.w), ac2[p][3]);
    }
  }
}

// Fused q-projection + flash attention (no-max) + out projection.
// Block = 256 threads = 4 waves = 2 row-octets x 2 key-halves; 16 rows/block.
// Lane = (rp, h, ks): ks = lane&3 (key split), h = (lane>>2)&7 (head),
// rp = lane>>5 (row-pair-group: rows 4*rp..4*rp+3 of the octet).
// rp=0/1 lanes issue IDENTICAL K/V addresses -> TA line work is shared.
// Each wave: 8 rows x 1024 keys (64 tiles of 16 keys), register dbuf.
// Prologue checks the wave's 256 mask words; all-ones -> maskless hot loop.
// Grid = NB*SEQ/16 = 512. launch_bounds (256,2): proven no-spill budget.
__global__ __launch_bounds__(256, 2) void attn_kernel(
    const float* __restrict__ query, const uint* __restrict__ pmw,
    const float* __restrict__ Kp, const float* __restrict__ Vp,
    const float* __restrict__ Wq, const float* __restrict__ bq,
    const float* __restrict__ Wo, const float* __restrict__ bo,
    float* __restrict__ out) {
  __shared__ float sWq[EMB][EMB];
  __shared__ float sWo[EMB][EMB];
  __shared__ float sbq[EMB];
  __shared__ float sbo[EMB];
  __shared__ float sX[16][EMB];
  __shared__ float sCtx[16][EMB + 1];
  __shared__ float sPart[2][16][EMB];   // [khalf][row][4h+d] partial ac
  __shared__ float sL[2][16][HEADS];    // [khalf][row][h]    partial l

  int t = threadIdx.x;
  int n = blockIdx.x >> 7;        // 128 q-tiles (of 16 rows) per batch
  int qt = blockIdx.x & 127;
  int qrow0 = qt * 16;

  int w = t >> 6;                 // wave 0..3
  int octet = w >> 1;             // row-octet 0..1 (rows 8*octet..+7)
  int kh = w & 1;                 // key half
  int lane = t & 63;
  int ks = lane & 3;              // key split 0..3
  int h = (lane >> 2) & 7;        // head
  int rp = lane >> 5;             // row-pair-group 0..1
  int rbl = 8 * octet + 4 * rp;   // this lane's first local row

  for (int i = t; i < EMB * EMB; i += 256) {
    sWq[i >> 5][i & 31] = Wq[i];
    sWo[i >> 5][i & 31] = Wo[i];
  }
  if (t < EMB) { sbq[t] = bq[t]; sbo[t] = bo[t]; }
#pragma unroll
  for (int rr = 0; rr < 2; ++rr) {
    int r = (t >> 5) + 8 * rr, c = t & 31;
    sX[r][c] = query[((size_t)n * SEQ + qrow0 + r) * EMB + c];
  }
  __syncthreads();

  // q projection for this lane's 4 rows x head h's 4 dims,
  // scaled by (1/sqrt(32))*log2(e).
  const float SC = 0.17677669529663687f * 1.4426950408889634f;
  float q[4][4];
#pragma unroll
  for (int r = 0; r < 4; ++r)
#pragma unroll
    for (int d = 0; d < 4; ++d) q[r][d] = sbq[4 * h + d];
#pragma unroll
  for (int j = 0; j < EMB; ++j) {
    float w0 = sWq[j][4 * h + 0], w1 = sWq[j][4 * h + 1];
    float w2 = sWq[j][4 * h + 2], w3 = sWq[j][4 * h + 3];
#pragma unroll
    for (int r = 0; r < 4; ++r) {
      float x = sX[rbl + r][j];
      q[r][0] = fmaf(x, w0, q[r][0]);
      q[r][1] = fmaf(x, w1, q[r][1]);
      q[r][2] = fmaf(x, w2, q[r][2]);
      q[r][3] = fmaf(x, w3, q[r][3]);
    }
  }
  v2f q2[2][4];
#pragma unroll
  for (int p = 0; p < 2; ++p)
#pragma unroll
    for (int d = 0; d < 4; ++d) {
      q2[p][d].x = q[2 * p][d] * SC;
      q2[p][d].y = q[2 * p + 1][d] * SC;
    }

  // prologue: AND this wave's 256 mask words (8 rows x 32 words)
  const uint* mbase = pmw + ((size_t)n * SEQ + qrow0 + 8 * octet) * (SEQ / 32) + kh * 32;
  {
    int wl = lane & 7, rl = lane >> 3;   // 8 words x 8 rows
    const uint* mr = mbase + (size_t)rl * 64;
  }
  int wl = lane & 7, rl = lane >> 3;
  const uint* mr = mbase + (size_t)rl * 64;
  uint myand = mr[wl] & mr[wl + 8] & mr[wl + 16] & mr[wl + 24];
  bool allones = __all(myand == 0xFFFFFFFFu);

  const float* kptr = Kp + (size_t)n * SEQ * EMB + (size_t)kh * 1024 * EMB
                         + (size_t)(4 * ks) * EMB + 4 * h;
  const float* vptr = Vp + (size_t)n * SEQ * EMB + (size_t)kh * 1024 * EMB
                         + (size_t)(4 * ks) * EMB + 4 * h;

  v2f l2[2], ac2[2][4];
#pragma unroll
  for (int p = 0; p < 2; ++p) {
    l2[p] = splat2(0.0f);
#pragma unroll
    for (int d = 0; d < 4; ++d) ac2[p][d] = splat2(0.0f);
  }

  if (allones) {
    // hot path: no mask loads, no mask ALU; 64 tiles, register double-buffer
    float4 ka[4], va[4], kb[4], vb[4];
    load_tile16(kptr, vptr, ka, va);
    for (int i = 0; i < 31; ++i) {
      load_tile16(kptr, vptr, kb, vb);
      compute_tile16(ka, va, q2, l2, ac2);
      load_tile16(kptr, vptr, ka, va);
      compute_tile16(kb, vb, q2, l2, ac2);
    }
    load_tile16(kptr, vptr, kb, vb);
    compute_tile16(ka, va, q2, l2, ac2);
    compute_tile16(kb, vb, q2, l2, ac2);
  } else {
    // cold path: per-tile mask words (rows rbl..rbl+3), simple loop
    const uint* mp = pmw + ((size_t)n * SEQ + qrow0 + rbl) * (SEQ / 32) + kh * 32;
    for (int tile = 0; tile < 64; ++tile) {
      float4 ka[4], va[4];
      load_tile16(kptr, vptr, ka, va);
      uint MW[4];
#pragma unroll
      for (int rr = 0; rr < 4; ++rr) MW[rr] = mp[(size_t)rr * 64 + (tile >> 1)];
      compute_tile16_masked(ka, va, MW, tile, ks, q2, l2, ac2);
    }
  }

  // merge the 4 k-split partials within the wave (butterfly over lane bits 0-1)
#pragma unroll
  for (int d = 1; d <= 2; d <<= 1) {
#pragma unroll
    for (int p = 0; p < 2; ++p) {
      l2[p].x += __shfl_xor(l2[p].x, d);
      l2[p].y += __shfl_xor(l2[p].y, d);
#pragma unroll
      for (int e = 0; e < 4; ++e) {
        ac2[p][e].x += __shfl_xor(ac2[p][e].x, d);
        ac2[p][e].y += __shfl_xor(ac2[p][e].y, d);
      }
    }
  }

  // stash this wave's half-range partials (ks picks the dim to write)
#pragma unroll
  for (int p = 0; p < 2; ++p) {
    int r0 = rbl + 2 * p;
    float vA = (ks == 0) ? ac2[p][0].x : (ks == 1) ? ac2[p][1].x
             : (ks == 2) ? ac2[p][2].x : ac2[p][3].x;
    float vB = (ks == 0) ? ac2[p][0].y : (ks == 1) ? ac2[p][1].y
             : (ks == 2) ? ac2[p][2].y : ac2[p][3].y;
    sPart[kh][r0 + 0][4 * h + ks] = vA;
    sPart[kh][r0 + 1][4 * h + ks] = vB;
    if (ks == 0) {
      sL[kh][r0 + 0][h] = l2[p].x;
      sL[kh][r0 + 1][h] = l2[p].y;
    }
  }
  __syncthreads();

  // combine halves + normalize: 16 rows x 32 cols, 2 per thread
#pragma unroll
  for (int rr = 0; rr < 2; ++rr) {
    int r = (t >> 5) + 8 * rr, c = t & 31, hh = (t & 31) >> 2;
    float num = sPart[0][r][c] + sPart[1][r][c];
    float den = sL[0][r][hh] + sL[1][r][hh];
    sCtx[r][c] = num * __builtin_amdgcn_rcpf(den);
  }
  __syncthreads();

  // output projection: out[row][e] = bo[e] + sum_j ctx[row][j] * Wo[j][e]
#pragma unroll
  for (int rr = 0; rr < 2; ++rr) {
    int r = (t >> 5) + 8 * rr, e = t & 31;
    float o = sbo[e];
#pragma unroll
    for (int j = 0; j < EMB; ++j) o = fmaf(sCtx[r][j], sWo[j][e], o);
    out[((size_t)n * SEQ + qrow0 + r) * EMB + e] = o;
  }
}

extern "C" void kernel_launch(void* const* d_in, const int* in_sizes, int n_in,
                              void* d_out, int out_size, void* d_ws, size_t ws_size,
                              hipStream_t stream) {
  const float* query = (const float*)d_in[0];
  const float* key   = (const float*)d_in[1];
  const float* value = (const float*)d_in[2];
  const int*   mask  = (const int*)d_in[3];
  const float* Wq = (const float*)d_in[4];
  const float* bq = (const float*)d_in[5];
  const float* Wk = (const float*)d_in[6];
  const float* bk = (const float*)d_in[7];
  const float* Wv = (const float*)d_in[8];
  const float* bv = (const float*)d_in[9];
  const float* Wo = (const float*)d_in[10];
  const float* bo = (const float*)d_in[11];
  float* out = (float*)d_out;

  float* Kp = (float*)d_ws;                          // 1 MB
  float* Vp = Kp + (size_t)NB * SEQ * EMB;           // 1 MB
  uint* pmw = (uint*)(Vp + (size_t)NB * SEQ * EMB);  // 2 MB packed mask bits

  const int packBlocks = NB * SEQ * SEQ / 4 / 256;   // 16384
  const int projBlocks = 2 * NB * SEQ / 8;           // 2048
  pack_proj_kernel<<<dim3(packBlocks + projBlocks), dim3(256), 0, stream>>>(
      mask, pmw, key, value, Wk, bk, Wv, bv, Kp, Vp);
  attn_kernel<<<dim3(NB * (SEQ / 16)), dim3(256), 0, stream>>>(
      query, pmw, Kp, Vp, Wq, bq, Wo, bo, out);
}

// Round 11
// 58.985 us; speedup vs baseline: 2.3258x; 2.3258x over previous
//
#include <hip/hip_runtime.h>

#define NB 4
#define SEQ 2048
#define EMB 32
#define HEADS 8
#define HD 4

typedef float v2f __attribute__((ext_vector_type(2)));
typedef unsigned int uint;

__device__ __forceinline__ v2f splat2(float x) { v2f r; r.x = x; r.y = x; return r; }
__device__ __forceinline__ v2f pkfma(v2f a, v2f b, v2f c) {
  return __builtin_elementwise_fma(a, b, c);
}

// Fused: mask bit-pack (blocks [0, 16384)) + K/V projections (blocks after).
__global__ __launch_bounds__(256) void pack_proj_kernel(
    const int* __restrict__ mask, uint* __restrict__ pmw,
    const float* __restrict__ key, const float* __restrict__ value,
    const float* __restrict__ Wk, const float* __restrict__ bk,
    const float* __restrict__ Wv, const float* __restrict__ bv,
    float* __restrict__ Kp, float* __restrict__ Vp) {
  const int packBlocks = NB * SEQ * SEQ / 4 / 256;   // 16384
  if (blockIdx.x < packBlocks) {
    // mask (N,1,Q,K) int32 -> 1 bit per key (bit b of word w = key 32w+b).
    int g = blockIdx.x * 256 + threadIdx.x;          // int4 index
    const int4 v = ((const int4*)mask)[g];
    uint nib = (uint)(v.x != 0) | ((uint)(v.y != 0) << 1) |
               ((uint)(v.z != 0) << 2) | ((uint)(v.w != 0) << 3);
    int lane = threadIdx.x & 63;
    uint w = nib << (4 * (lane & 7));
    w |= __shfl_xor(w, 1);
    w |= __shfl_xor(w, 2);
    w |= __shfl_xor(w, 4);
    if ((lane & 7) == 0) pmw[g >> 3] = w;
  } else {
    const int half = NB * SEQ / 8;                   // 1024
    int blk2 = blockIdx.x - packBlocks;
    bool isV = blk2 >= half;
    const float* X = isV ? value : key;
    const float* W = isV ? Wv : Wk;
    const float* b = isV ? bv : bk;
    float* P = isV ? Vp : Kp;
    int blk = isV ? (blk2 - half) : blk2;

    __shared__ float sW[EMB][EMB];
    __shared__ float sb[EMB];
    __shared__ float sX[8][EMB];
    int t = threadIdx.x;
    for (int i = t; i < EMB * EMB; i += 256) sW[i >> 5][i & 31] = W[i];
    if (t < EMB) sb[t] = b[t];
    size_t row0 = (size_t)blk * 8;
    int r = t >> 5, c = t & 31;
    sX[r][c] = X[(row0 + r) * EMB + c];
    __syncthreads();
    float acc = sb[c];
#pragma unroll
    for (int d = 0; d < EMB; ++d) acc = fmaf(sX[r][d], sW[d][c], acc);
    P[(row0 + r) * EMB + c] = acc;
  }
}

// 32-key tile, round-8 addressing: lane (h, ks) -> 64 DISTINCT float4 per
// load instruction (full 1 KB/instr; duplicate-address scheme of r10 was 2x
// slower). KK[j]/VV[j] = key (4*ks+j), dims 4h..4h+3.
__device__ __forceinline__ void load_tile(
    const float*& kptr, const float*& vptr,
    float4 (&KK)[4], float4 (&VV)[4]) {
  KK[0] = *(const float4*)(kptr);
  KK[1] = *(const float4*)(kptr + EMB);
  KK[2] = *(const float4*)(kptr + 2 * EMB);
  KK[3] = *(const float4*)(kptr + 3 * EMB);
  VV[0] = *(const float4*)(vptr);
  VV[1] = *(const float4*)(vptr + EMB);
  VV[2] = *(const float4*)(vptr + 2 * EMB);
  VV[3] = *(const float4*)(vptr + 3 * EMB);
  kptr += 32 * EMB; vptr += 32 * EMB;
}

// No-max softmax, maskless fast path. R=8 rows/thread as 4 v2f row-pairs.
__device__ __forceinline__ void compute_tile(
    const float4 (&KK)[4], const float4 (&VV)[4],
    const v2f (&q2)[4][4], v2f (&l2)[4], v2f (&ac2)[4][4]) {
#pragma unroll
  for (int p = 0; p < 4; ++p) {
    v2f pf[4];
#pragma unroll
    for (int j = 0; j < 4; ++j) {
      const float4 kk = KK[j];
      v2f s = pkfma(q2[p][0], splat2(kk.x),
              pkfma(q2[p][1], splat2(kk.y),
              pkfma(q2[p][2], splat2(kk.z), q2[p][3] * splat2(kk.w))));
      pf[j].x = __builtin_amdgcn_exp2f(s.x);
      pf[j].y = __builtin_amdgcn_exp2f(s.y);
    }
    l2[p] += (pf[0] + pf[1]) + (pf[2] + pf[3]);
#pragma unroll
    for (int j = 0; j < 4; ++j) {
      const float4 vv = VV[j];
      ac2[p][0] = pkfma(pf[j], splat2(vv.x), ac2[p][0]);
      ac2[p][1] = pkfma(pf[j], splat2(vv.y), ac2[p][1]);
      ac2[p][2] = pkfma(pf[j], splat2(vv.z), ac2[p][2]);
      ac2[p][3] = pkfma(pf[j], splat2(vv.w), ac2[p][3]);
    }
  }
}

// Masked variant (cold path; bench mask is all-ones so not taken there).
__device__ __forceinline__ void compute_tile_masked(
    const float4 (&KK)[4], const float4 (&VV)[4],
    const uint (&MW)[8], int ks4,
    const v2f (&q2)[4][4], v2f (&l2)[4], v2f (&ac2)[4][4]) {
#pragma unroll
  for (int p = 0; p < 4; ++p) {
    v2f pf[4];
#pragma unroll
    for (int j = 0; j < 4; ++j) {
      const float4 kk = KK[j];
      v2f s = pkfma(q2[p][0], splat2(kk.x),
              pkfma(q2[p][1], splat2(kk.y),
              pkfma(q2[p][2], splat2(kk.z), q2[p][3] * splat2(kk.w))));
      pf[j].x = ((MW[2 * p + 0] >> (ks4 + j)) & 1u) ? __builtin_amdgcn_exp2f(s.x) : 0.0f;
      pf[j].y = ((MW[2 * p + 1] >> (ks4 + j)) & 1u) ? __builtin_amdgcn_exp2f(s.y) : 0.0f;
    }
    l2[p] += (pf[0] + pf[1]) + (pf[2] + pf[3]);
#pragma unroll
    for (int j = 0; j < 4; ++j) {
      const float4 vv = VV[j];
      ac2[p][0] = pkfma(pf[j], splat2(vv.x), ac2[p][0]);
      ac2[p][1] = pkfma(pf[j], splat2(vv.y), ac2[p][1]);
      ac2[p][2] = pkfma(pf[j], splat2(vv.z), ac2[p][2]);
      ac2[p][3] = pkfma(pf[j], splat2(vv.w), ac2[p][3]);
    }
  }
}

// Fused q-projection + flash attention (no-max) + out projection.
// Block = 256 threads = 4 waves = 2 row-octets x 2 key-halves; 16 rows/block.
// Wave: R=8 rows/thread (octet rbl..rbl+7), 1024 keys (32 tiles of 32 keys).
// Lane: head h = lane&7, k-split ks = lane>>3 (distinct addresses, r8-style).
// Prologue ANDs the wave's 256 mask words -> maskless hot loop (saves 1/3 of
// VMEM instructions); masked cold path for generality.
// Grid = NB*SEQ/16 = 512. launch_bounds (256,2): proven no-spill budget.
__global__ __launch_bounds__(256, 2) void attn_kernel(
    const float* __restrict__ query, const uint* __restrict__ pmw,
    const float* __restrict__ Kp, const float* __restrict__ Vp,
    const float* __restrict__ Wq, const float* __restrict__ bq,
    const float* __restrict__ Wo, const float* __restrict__ bo,
    float* __restrict__ out) {
  __shared__ float sWq[EMB][EMB];
  __shared__ float sWo[EMB][EMB];
  __shared__ float sbq[EMB];
  __shared__ float sbo[EMB];
  __shared__ float sX[16][EMB];
  __shared__ float sCtx[16][EMB + 1];
  __shared__ float sPart[2][16][EMB];   // [khalf][row][4h+d] partial ac
  __shared__ float sL[2][16][HEADS];    // [khalf][row][h]    partial l

  int t = threadIdx.x;
  int n = blockIdx.x >> 7;        // 128 q-tiles (of 16 rows) per batch
  int qt = blockIdx.x & 127;
  int qrow0 = qt * 16;

  int w = t >> 6;                 // wave 0..3
  int octet = w >> 1;             // row-octet 0..1 (rows 8*octet..+7)
  int kh = w & 1;                 // key half
  int lane = t & 63;
  int h = lane & 7;               // head
  int ks = lane >> 3;             // key split 0..7
  int ks4 = 4 * ks;
  int rbl = 8 * octet;

  for (int i = t; i < EMB * EMB; i += 256) {
    sWq[i >> 5][i & 31] = Wq[i];
    sWo[i >> 5][i & 31] = Wo[i];
  }
  if (t < EMB) { sbq[t] = bq[t]; sbo[t] = bo[t]; }
#pragma unroll
  for (int rr = 0; rr < 2; ++rr) {
    int r = (t >> 5) + 8 * rr, c = t & 31;
    sX[r][c] = query[((size_t)n * SEQ + qrow0 + r) * EMB + c];
  }
  __syncthreads();

  // q projection for this thread's 8 rows x head h's 4 dims, packed as
  // 4 row-pair v2f, scaled by (1/sqrt(32))*log2(e).
  const float SC = 0.17677669529663687f * 1.4426950408889634f;
  v2f q2[4][4];
#pragma unroll
  for (int p = 0; p < 4; ++p)
#pragma unroll
    for (int d = 0; d < 4; ++d) q2[p][d] = splat2(sbq[4 * h + d]);
#pragma unroll
  for (int j = 0; j < EMB; ++j) {
    float w0 = sWq[j][4 * h + 0], w1 = sWq[j][4 * h + 1];
    float w2 = sWq[j][4 * h + 2], w3 = sWq[j][4 * h + 3];
#pragma unroll
    for (int p = 0; p < 4; ++p) {
      v2f x;
      x.x = sX[rbl + 2 * p + 0][j];
      x.y = sX[rbl + 2 * p + 1][j];
      q2[p][0] = pkfma(x, splat2(w0), q2[p][0]);
      q2[p][1] = pkfma(x, splat2(w1), q2[p][1]);
      q2[p][2] = pkfma(x, splat2(w2), q2[p][2]);
      q2[p][3] = pkfma(x, splat2(w3), q2[p][3]);
    }
  }
#pragma unroll
  for (int p = 0; p < 4; ++p)
#pragma unroll
    for (int d = 0; d < 4; ++d) q2[p][d] *= splat2(SC);

  // prologue: AND this wave's 256 mask words (8 rows x 32 words, khalf range)
  const uint* mbase = pmw + ((size_t)n * SEQ + qrow0 + rbl) * (SEQ / 32) + kh * 32;
  int wl = lane & 7, rl = lane >> 3;
  const uint* mr = mbase + (size_t)rl * 64;
  uint myand = mr[wl] & mr[wl + 8] & mr[wl + 16] & mr[wl + 24];
  bool allones = __all(myand == 0xFFFFFFFFu);

  const float* kptr = Kp + (size_t)n * SEQ * EMB + (size_t)kh * 1024 * EMB
                         + (size_t)ks4 * EMB + 4 * h;
  const float* vptr = Vp + (size_t)n * SEQ * EMB + (size_t)kh * 1024 * EMB
                         + (size_t)ks4 * EMB + 4 * h;

  v2f l2[4], ac2[4][4];
#pragma unroll
  for (int p = 0; p < 4; ++p) {
    l2[p] = splat2(0.0f);
#pragma unroll
    for (int d = 0; d < 4; ++d) ac2[p][d] = splat2(0.0f);
  }

  if (allones) {
    // hot path: zero mask loads; 32 tiles, register double-buffer
    float4 ka[4], va[4], kb[4], vb[4];
    load_tile(kptr, vptr, ka, va);
    for (int i = 0; i < 15; ++i) {
      load_tile(kptr, vptr, kb, vb);
      compute_tile(ka, va, q2, l2, ac2);
      load_tile(kptr, vptr, ka, va);
      compute_tile(kb, vb, q2, l2, ac2);
    }
    load_tile(kptr, vptr, kb, vb);
    compute_tile(ka, va, q2, l2, ac2);
    compute_tile(kb, vb, q2, l2, ac2);
  } else {
    // cold path: per-tile mask words for the 8 rows
    for (int tile = 0; tile < 32; ++tile) {
      float4 ka[4], va[4];
      load_tile(kptr, vptr, ka, va);
      uint MW[8];
#pragma unroll
      for (int rr = 0; rr < 8; ++rr) MW[rr] = mbase[(size_t)rr * 64 + tile];
      compute_tile_masked(ka, va, MW, ks4, q2, l2, ac2);
    }
  }

  // merge the 8 k-split partials within the wave (butterfly over lane bits 3-5)
#pragma unroll
  for (int d = 8; d <= 32; d <<= 1) {
#pragma unroll
    for (int p = 0; p < 4; ++p) {
      l2[p].x += __shfl_xor(l2[p].x, d);
      l2[p].y += __shfl_xor(l2[p].y, d);
#pragma unroll
      for (int e = 0; e < 4; ++e) {
        ac2[p][e].x += __shfl_xor(ac2[p][e].x, d);
        ac2[p][e].y += __shfl_xor(ac2[p][e].y, d);
      }
    }
  }

  // stash this wave's half-range partials
#pragma unroll
  for (int p = 0; p < 4; ++p) {
    int r0 = rbl + 2 * p;
    if (ks < 4) {
      float vA = (ks == 0) ? ac2[p][0].x : (ks == 1) ? ac2[p][1].x
               : (ks == 2) ? ac2[p][2].x : ac2[p][3].x;
      float vB = (ks == 0) ? ac2[p][0].y : (ks == 1) ? ac2[p][1].y
               : (ks == 2) ? ac2[p][2].y : ac2[p][3].y;
      sPart[kh][r0 + 0][4 * h + ks] = vA;
      sPart[kh][r0 + 1][4 * h + ks] = vB;
    } else if (ks == 4) {
      sL[kh][r0 + 0][h] = l2[p].x;
      sL[kh][r0 + 1][h] = l2[p].y;
    }
  }
  __syncthreads();

  // combine halves + normalize: 16 rows x 32 cols, 2 per thread
#pragma unroll
  for (int rr = 0; rr < 2; ++rr) {
    int r = (t >> 5) + 8 * rr, c = t & 31, hh = (t & 31) >> 2;
    float num = sPart[0][r][c] + sPart[1][r][c];
    float den = sL[0][r][hh] + sL[1][r][hh];
    sCtx[r][c] = num * __builtin_amdgcn_rcpf(den);
  }
  __syncthreads();

  // output projection: out[row][e] = bo[e] + sum_j ctx[row][j] * Wo[j][e]
#pragma unroll
  for (int rr = 0; rr < 2; ++rr) {
    int r = (t >> 5) + 8 * rr, e = t & 31;
    float o = sbo[e];
#pragma unroll
    for (int j = 0; j < EMB; ++j) o = fmaf(sCtx[r][j], sWo[j][e], o);
    out[((size_t)n * SEQ + qrow0 + r) * EMB + e] = o;
  }
}

extern "C" void kernel_launch(void* const* d_in, const int* in_sizes, int n_in,
                              void* d_out, int out_size, void* d_ws, size_t ws_size,
                              hipStream_t stream) {
  const float* query = (const float*)d_in[0];
  const float* key   = (const float*)d_in[1];
  const float* value = (const float*)d_in[2];
  const int*   mask  = (const int*)d_in[3];
  const float* Wq = (const float*)d_in[4];
  const float* bq = (const float*)d_in[5];
  const float* Wk = (const float*)d_in[6];
  const float* bk = (const float*)d_in[7];
  const float* Wv = (const float*)d_in[8];
  const float* bv = (const float*)d_in[9];
  const float* Wo = (const float*)d_in[10];
  const float* bo = (const float*)d_in[11];
  float* out = (float*)d_out;

  float* Kp = (float*)d_ws;                          // 1 MB
  float* Vp = Kp + (size_t)NB * SEQ * EMB;           // 1 MB
  uint* pmw = (uint*)(Vp + (size_t)NB * SEQ * EMB);  // 2 MB packed mask bits

  const int packBlocks = NB * SEQ * SEQ / 4 / 256;   // 16384
  const int projBlocks = 2 * NB * SEQ / 8;           // 2048
  pack_proj_kernel<<<dim3(packBlocks + projBlocks), dim3(256), 0, stream>>>(
      mask, pmw, key, value, Wk, bk, Wv, bv, Kp, Vp);
  attn_kernel<<<dim3(NB * (SEQ / 16)), dim3(256), 0, stream>>>(
      query, pmw, Kp, Vp, Wq, bq, Wo, bo, out);
}